// Round 1
// baseline (619.484 us; speedup 1.0000x reference)
//
#include <hip/hip_runtime.h>
#include <hip/hip_bf16.h>

// GroupedLinear: out[s_e:e_e] = x[s_e:e_e] @ W[e]^T
// T=16384 tokens, IN(K)=2048, OUT(N)=5632, E=8. fp32 in/out, bf16 MFMA compute.

#define T_TOK 16384
#define K_IN  2048
#define N_OUT 5632
#define NEXP  8

#define BM 128
#define BN 128
#define BK 64
#define MT (T_TOK / BM)   // 128 m-tiles
#define NTILE (N_OUT / BN) // 44 n-tiles

typedef __attribute__((ext_vector_type(8))) short short8;
typedef __attribute__((ext_vector_type(4))) float f32x4;
typedef unsigned short ushort_t;

__device__ __forceinline__ ushort_t f2bf(float x) {
  __hip_bfloat16 h = __float2bfloat16(x);  // RNE
  return *reinterpret_cast<ushort_t*>(&h);
}

// ---------------- fp32 -> bf16 conversion prepass (vectorized) ----------------
__global__ void __launch_bounds__(256) cvt_kernel(const float* __restrict__ in,
                                                  ushort_t* __restrict__ out,
                                                  int n8) {
  int i = blockIdx.x * blockDim.x + threadIdx.x;
  int stride = gridDim.x * blockDim.x;
  for (; i < n8; i += stride) {
    const float4* p = (const float4*)in + (size_t)i * 2;
    float4 a = p[0], b = p[1];
    short8 v;
    v[0] = (short)f2bf(a.x); v[1] = (short)f2bf(a.y);
    v[2] = (short)f2bf(a.z); v[3] = (short)f2bf(a.w);
    v[4] = (short)f2bf(b.x); v[5] = (short)f2bf(b.y);
    v[6] = (short)f2bf(b.z); v[7] = (short)f2bf(b.w);
    *((short8*)out + i) = v;
  }
}

// ---------------- grouped GEMM, m97 structure ----------------
// BF16SRC=true : A/W already bf16 in ws, stage via global_load_lds (16B).
// BF16SRC=false: A/W fp32 in global, reg-stage + convert inline (ws-free fallback).
template <bool BF16SRC>
__global__ void __launch_bounds__(256) gemm_grouped(
    const ushort_t* __restrict__ abf, const ushort_t* __restrict__ wbf,
    const float* __restrict__ af, const float* __restrict__ wf,
    const int* __restrict__ offs, float* __restrict__ out) {
  __shared__ __align__(16) ushort_t lsA[BM * BK];
  __shared__ __align__(16) ushort_t lsB[BN * BK];

  // XCD-aware bijective swizzle (grid 5632 % 8 == 0)
  int bid = blockIdx.x;
  int wg = (bid & 7) * ((MT * NTILE) >> 3) + (bid >> 3);
  int tm = wg / NTILE;
  int tn = wg - tm * NTILE;

  const int t = threadIdx.x;
  const int w = t >> 6;      // wave 0..3
  const int l = t & 63;      // lane

  const int row0 = tm * BM;
  // expert lookup: offs[e] <= row0 < offs[e+1]
  int e = 0;
#pragma unroll
  for (int i = 1; i < NEXP; ++i) e += (row0 >= offs[i]) ? 1 : 0;
  const size_t wbase = (size_t)e * ((size_t)N_OUT * K_IN);

  f32x4 acc[4][4];
#pragma unroll
  for (int i = 0; i < 4; ++i)
#pragma unroll
    for (int j = 0; j < 4; ++j)
#pragma unroll
      for (int r = 0; r < 4; ++r) acc[i][j][r] = 0.f;

  const int wm = w >> 1, wn = w & 1;       // 2x2 wave grid, each 64x64
  const int rA = wm * 64 + (l & 15);       // A row within tile (frag base)
  const int rB = wn * 64 + (l & 15);       // W row (=output col) within tile
  const int kgo = (l >> 4) * 8;            // k-group offset within 32-slice

  for (int kt = 0; kt < K_IN / BK; ++kt) {
    const int k0 = kt * BK;
    if (kt) __syncthreads();  // previous compute done before overwrite

    // ---- stage A tile: 128x64 bf16 = 16KB = 16 wave-chunks of 1KB ----
#pragma unroll
    for (int p = 0; p < 4; ++p) {
      const int wc = p * 4 + w;          // wave-chunk 0..15
      const int ia = wc * 64 + l;        // 16B-chunk index 0..1023
      const int ra = ia >> 3;            // row 0..127
      const int ca = (ia & 7) * 8;       // col (elements)
      if constexpr (BF16SRC) {
        const ushort_t* g = abf + (size_t)(row0 + ra) * K_IN + k0 + ca;
        __builtin_amdgcn_global_load_lds(
            (const __attribute__((address_space(1))) void*)g,
            (__attribute__((address_space(3))) void*)&lsA[wc * 512], 16, 0, 0);
      } else {
        const float4* g = (const float4*)(af + (size_t)(row0 + ra) * K_IN + k0 + ca);
        float4 a = g[0], b = g[1];
        short8 v;
        v[0] = (short)f2bf(a.x); v[1] = (short)f2bf(a.y);
        v[2] = (short)f2bf(a.z); v[3] = (short)f2bf(a.w);
        v[4] = (short)f2bf(b.x); v[5] = (short)f2bf(b.y);
        v[6] = (short)f2bf(b.z); v[7] = (short)f2bf(b.w);
        *(short8*)&lsA[ia * 8] = v;
      }
    }
    // ---- stage B tile: W rows tn*128..+128, same chunking ----
#pragma unroll
    for (int p = 0; p < 4; ++p) {
      const int wc = p * 4 + w;
      const int ib = wc * 64 + l;
      const int rb = ib >> 3;
      const int cb = (ib & 7) * 8;
      if constexpr (BF16SRC) {
        const ushort_t* g = wbf + wbase + (size_t)(tn * BN + rb) * K_IN + k0 + cb;
        __builtin_amdgcn_global_load_lds(
            (const __attribute__((address_space(1))) void*)g,
            (__attribute__((address_space(3))) void*)&lsB[wc * 512], 16, 0, 0);
      } else {
        const float4* g = (const float4*)(wf + wbase + (size_t)(tn * BN + rb) * K_IN + k0 + cb);
        float4 a = g[0], b = g[1];
        short8 v;
        v[0] = (short)f2bf(a.x); v[1] = (short)f2bf(a.y);
        v[2] = (short)f2bf(a.z); v[3] = (short)f2bf(a.w);
        v[4] = (short)f2bf(b.x); v[5] = (short)f2bf(b.y);
        v[6] = (short)f2bf(b.z); v[7] = (short)f2bf(b.w);
        *(short8*)&lsB[ib * 8] = v;
      }
    }
    __syncthreads();  // compiler drains vmcnt before barrier

    // ---- compute: 2 k-steps of 32, 16 MFMA each per wave ----
#pragma unroll
    for (int s = 0; s < 2; ++s) {
      const int ko = s * 32 + kgo;
      short8 aF[4], bF[4];
#pragma unroll
      for (int i = 0; i < 4; ++i)
        aF[i] = *(const short8*)&lsA[(rA + i * 16) * BK + ko];
#pragma unroll
      for (int j = 0; j < 4; ++j)
        bF[j] = *(const short8*)&lsB[(rB + j * 16) * BK + ko];
#pragma unroll
      for (int i = 0; i < 4; ++i)
#pragma unroll
        for (int j = 0; j < 4; ++j)
          acc[i][j] = __builtin_amdgcn_mfma_f32_16x16x32_bf16(aF[i], bF[j],
                                                              acc[i][j], 0, 0, 0);
    }
  }

  // ---- epilogue: C/D layout col=lane&15, row=(lane>>4)*4+reg ----
  const int cr = (l >> 4) * 4;
  const int cc = l & 15;
  float* ob = out + (size_t)(row0 + wm * 64) * N_OUT + tn * BN + wn * 64;
#pragma unroll
  for (int i = 0; i < 4; ++i)
#pragma unroll
    for (int j = 0; j < 4; ++j)
#pragma unroll
      for (int r = 0; r < 4; ++r)
        ob[(size_t)(i * 16 + cr + r) * N_OUT + j * 16 + cc] = acc[i][j][r];
}

extern "C" void kernel_launch(void* const* d_in, const int* in_sizes, int n_in,
                              void* d_out, int out_size, void* d_ws, size_t ws_size,
                              hipStream_t stream) {
  const float* x = (const float*)d_in[0];
  const float* wt = (const float*)d_in[1];
  const int* offs = (const int*)d_in[2];
  float* out = (float*)d_out;

  const size_t nA = (size_t)T_TOK * K_IN;          // 33,554,432
  const size_t nW = (size_t)NEXP * N_OUT * K_IN;   // 92,274,688
  const size_t need = (nA + nW) * sizeof(ushort_t); // 240 MiB

  if (ws_size >= need) {
    ushort_t* abf = (ushort_t*)d_ws;
    ushort_t* wbf = abf + nA;
    cvt_kernel<<<2048, 256, 0, stream>>>(x, abf, (int)(nA / 8));
    cvt_kernel<<<2048, 256, 0, stream>>>(wt, wbf, (int)(nW / 8));
    gemm_grouped<true><<<MT * NTILE, 256, 0, stream>>>(abf, wbf, nullptr, nullptr,
                                                       offs, out);
  } else {
    gemm_grouped<false><<<MT * NTILE, 256, 0, stream>>>(nullptr, nullptr, x, wt,
                                                        offs, out);
  }
}

// Round 2
// 516.388 us; speedup vs baseline: 1.1996x; 1.1996x over previous
//
#include <hip/hip_runtime.h>
#include <hip/hip_bf16.h>

// GroupedLinear: out[s_e:e_e] = x[s_e:e_e] @ W[e]^T
// T=16384, K=2048, N=5632, E=8. fp32 in/out, bf16 MFMA compute.
// 256x256 8-phase deep-pipelined grouped GEMM (T1+T2+T3+T4+T5).

#define T_TOK 16384
#define K_IN  2048
#define N_OUT 5632
#define NEXP  8

typedef __attribute__((ext_vector_type(8))) short short8;
typedef __attribute__((ext_vector_type(4))) float f32x4;
typedef unsigned short ushort_t;

__device__ __forceinline__ ushort_t f2bf(float x) {
  __hip_bfloat16 h = __float2bfloat16(x);  // RNE
  return *reinterpret_cast<ushort_t*>(&h);
}

// ---------------- fp32 -> bf16 conversion prepass ----------------
__global__ void __launch_bounds__(256) cvt_kernel(const float* __restrict__ in,
                                                  ushort_t* __restrict__ out,
                                                  int n8) {
  int i = blockIdx.x * blockDim.x + threadIdx.x;
  int stride = gridDim.x * blockDim.x;
  for (; i < n8; i += stride) {
    const float4* p = (const float4*)in + (size_t)i * 2;
    float4 a = p[0], b = p[1];
    short8 v;
    v[0] = (short)f2bf(a.x); v[1] = (short)f2bf(a.y);
    v[2] = (short)f2bf(a.z); v[3] = (short)f2bf(a.w);
    v[4] = (short)f2bf(b.x); v[5] = (short)f2bf(b.y);
    v[6] = (short)f2bf(b.z); v[7] = (short)f2bf(b.w);
    *((short8*)out + i) = v;
  }
}

// ---------------- 256x256 8-phase GEMM ----------------
#define MT2 64          // 16384/256
#define NT2 22          // 5632/256
#define GRID2 (MT2 * NT2)  // 1408, %8==0

#define BAR() do { asm volatile("" ::: "memory"); \
                   __builtin_amdgcn_s_barrier(); \
                   asm volatile("" ::: "memory"); } while (0)
#define VMCNT(n) asm volatile("s_waitcnt vmcnt(" #n ")" ::: "memory")

// Swizzled fragment read: 2x short8 at k = s*32+kgo, row lr of a [128][64] bf16
// half-tile.  byte ^= (lr&7)<<4 spreads 16 same-col rows across 8 16B slots.
__device__ __forceinline__ void ld_frag(const ushort_t* reg, int lr, int kgo,
                                        short8* o) {
#pragma unroll
  for (int s = 0; s < 2; ++s) {
    int b = lr * 128 + ((((s * 32 + kgo) * 2)) ^ ((lr & 7) << 4));
    o[s] = *(const short8*)((const char*)reg + b);
  }
}

template <int M0>
__device__ __forceinline__ void mma_pair(f32x4 acc[8][4], const short8 a0[2],
                                         const short8 a1[2],
                                         const short8 bF[4][2]) {
  __builtin_amdgcn_s_setprio(1);
#pragma unroll
  for (int n = 0; n < 4; ++n)
#pragma unroll
    for (int s = 0; s < 2; ++s) {
      acc[M0][n] = __builtin_amdgcn_mfma_f32_16x16x32_bf16(a0[s], bF[n][s],
                                                           acc[M0][n], 0, 0, 0);
      acc[M0 + 1][n] = __builtin_amdgcn_mfma_f32_16x16x32_bf16(
          a1[s], bF[n][s], acc[M0 + 1][n], 0, 0, 0);
    }
  __builtin_amdgcn_s_setprio(0);
}

__global__ void __launch_bounds__(512, 2) gemm8(
    const ushort_t* __restrict__ abf, const ushort_t* __restrict__ wbf,
    const int* __restrict__ offs, float* __restrict__ out) {
  // [buf][mat 0=A/1=B][half][128 rows x 64 cols bf16] = 128 KiB
  __shared__ __align__(16) ushort_t lds[2][2][2][8192];

  int bid = blockIdx.x;
  int wg = (bid & 7) * (GRID2 / 8) + (bid >> 3);  // XCD swizzle, bijective
  int tm = wg / NT2;
  int tn = wg - tm * NT2;

  const int t = threadIdx.x;
  const int w = t >> 6;       // wave 0..7
  const int l = t & 63;
  const int wm = w >> 2;      // 0..1 : M-half of output
  const int wn = w & 3;       // 0..3 : N-quarter

  const int row0 = tm * 256;
  int e = 0;
#pragma unroll
  for (int i = 1; i < NEXP; ++i) e += (row0 >= offs[i]) ? 1 : 0;

  const ushort_t* aB = abf + (size_t)row0 * K_IN;
  const ushort_t* wB =
      wbf + (size_t)e * N_OUT * K_IN + (size_t)(tn * 256) * K_IN;

  // Stage one 128x64 half-tile (16 KB): wave w writes chunks 2w, 2w+1 (8 rows
  // each).  Linear LDS dest; global source col pre-swizzled: col8 ^= (row&7).
  auto stage = [&](const ushort_t* gbase, ushort_t* lreg) {
#pragma unroll
    for (int q = 0; q < 2; ++q) {
      int c = 2 * w + q;
      const ushort_t* src =
          gbase + (size_t)(c * 8 + (l >> 3)) * K_IN + ((l & 7) ^ (l >> 3)) * 8;
      __builtin_amdgcn_global_load_lds(
          (const __attribute__((address_space(1))) void*)src,
          (__attribute__((address_space(3))) void*)(lreg + c * 512), 16, 0, 0);
    }
  };

  f32x4 acc[8][4];
#pragma unroll
  for (int i = 0; i < 8; ++i)
#pragma unroll
    for (int j = 0; j < 4; ++j)
#pragma unroll
      for (int r = 0; r < 4; ++r) acc[i][j][r] = 0.f;

  const int kgo = (l >> 4) * 8;
  const int l15 = l & 15;
  const int lrB0 = (wn & 1) * 64 + l15;  // base row in B half (wn>>1)
  const size_t H = (size_t)128 * K_IN;   // half-tile row offset in global

  // ---- prologue: tile0 full -> b0, tile1.B -> b1.B ----
  stage(aB, &lds[0][0][0][0]);
  stage(aB + H, &lds[0][0][1][0]);
  stage(wB, &lds[0][1][0][0]);
  stage(wB + H, &lds[0][1][1][0]);
  stage(wB + 64, &lds[1][1][0][0]);
  stage(wB + H + 64, &lds[1][1][1][0]);
  VMCNT(4);  // wait tile0 (8 oldest), allow tile1.B (4)
  BAR();

  short8 bF[4][2];
#pragma unroll 1
  for (int J = 0; J < 16; ++J) {
    const size_t kO1 = (size_t)(2 * J + 1) * 64;
    const size_t kO2 = (size_t)(2 * J + 2) * 64;
    const size_t kO3 = (size_t)(2 * J + 3) * 64;
    const bool more = (J < 15);

    // ---- P1: buf0, m0-1; stage t(2J+1).A -> b1.A ----
    {
      short8 a0[2], a1[2];
#pragma unroll
      for (int n = 0; n < 4; ++n)
        ld_frag(&lds[0][1][wn >> 1][0], lrB0 + n * 16, kgo, bF[n]);
      ld_frag(&lds[0][0][wm][0], 0 * 16 + l15, kgo, a0);
      ld_frag(&lds[0][0][wm][0], 1 * 16 + l15, kgo, a1);
      stage(aB + kO1, &lds[1][0][0][0]);
      stage(aB + H + kO1, &lds[1][0][1][0]);
      BAR();
      mma_pair<0>(acc, a0, a1, bF);
      BAR();
    }
    // ---- P2: m2-3; stage t(2J+2).B0 -> b0.B0 ----
    {
      short8 a0[2], a1[2];
      ld_frag(&lds[0][0][wm][0], 2 * 16 + l15, kgo, a0);
      ld_frag(&lds[0][0][wm][0], 3 * 16 + l15, kgo, a1);
      if (more) stage(wB + kO2, &lds[0][1][0][0]);
      BAR();
      mma_pair<2>(acc, a0, a1, bF);
      BAR();
    }
    // ---- P3: m4-5; stage t(2J+2).B1 -> b0.B1 ----
    {
      short8 a0[2], a1[2];
      ld_frag(&lds[0][0][wm][0], 4 * 16 + l15, kgo, a0);
      ld_frag(&lds[0][0][wm][0], 5 * 16 + l15, kgo, a1);
      if (more) stage(wB + H + kO2, &lds[0][1][1][0]);
      BAR();
      mma_pair<4>(acc, a0, a1, bF);
      BAR();
    }
    // ---- P4: m6-7; no stage; counted vmcnt guards P5's reads of b1 ----
    {
      short8 a0[2], a1[2];
      ld_frag(&lds[0][0][wm][0], 6 * 16 + l15, kgo, a0);
      ld_frag(&lds[0][0][wm][0], 7 * 16 + l15, kgo, a1);
      BAR();
      mma_pair<6>(acc, a0, a1, bF);
      if (more) { VMCNT(4); } else { VMCNT(0); }
      BAR();
    }
    // ---- P5: buf1, m0-1; stage t(2J+2).A0 -> b0.A0 ----
    {
      short8 a0[2], a1[2];
#pragma unroll
      for (int n = 0; n < 4; ++n)
        ld_frag(&lds[1][1][wn >> 1][0], lrB0 + n * 16, kgo, bF[n]);
      ld_frag(&lds[1][0][wm][0], 0 * 16 + l15, kgo, a0);
      ld_frag(&lds[1][0][wm][0], 1 * 16 + l15, kgo, a1);
      if (more) stage(aB + kO2, &lds[0][0][0][0]);
      BAR();
      mma_pair<0>(acc, a0, a1, bF);
      BAR();
    }
    // ---- P6: m2-3; stage t(2J+2).A1 -> b0.A1 ----
    {
      short8 a0[2], a1[2];
      ld_frag(&lds[1][0][wm][0], 2 * 16 + l15, kgo, a0);
      ld_frag(&lds[1][0][wm][0], 3 * 16 + l15, kgo, a1);
      if (more) stage(aB + H + kO2, &lds[0][0][1][0]);
      BAR();
      mma_pair<2>(acc, a0, a1, bF);
      BAR();
    }
    // ---- P7: m4-5; stage t(2J+3).B0 -> b1.B0 ----
    {
      short8 a0[2], a1[2];
      ld_frag(&lds[1][0][wm][0], 4 * 16 + l15, kgo, a0);
      ld_frag(&lds[1][0][wm][0], 5 * 16 + l15, kgo, a1);
      if (more) stage(wB + kO3, &lds[1][1][0][0]);
      BAR();
      mma_pair<4>(acc, a0, a1, bF);
      BAR();
    }
    // ---- P8: m6-7; stage t(2J+3).B1 -> b1.B1; counted vmcnt for next P1 ----
    {
      short8 a0[2], a1[2];
      ld_frag(&lds[1][0][wm][0], 6 * 16 + l15, kgo, a0);
      ld_frag(&lds[1][0][wm][0], 7 * 16 + l15, kgo, a1);
      if (more) stage(wB + H + kO3, &lds[1][1][1][0]);
      BAR();
      mma_pair<6>(acc, a0, a1, bF);
      if (more) VMCNT(4);
      BAR();
    }
  }

  // ---- epilogue: C/D layout col=lane&15, row=(lane>>4)*4+reg ----
  const int cr = (l >> 4) * 4;
  const int cc = l & 15;
  float* ob = out + (size_t)(row0 + wm * 128) * N_OUT + tn * 256 + wn * 64;
#pragma unroll
  for (int m = 0; m < 8; ++m)
#pragma unroll
    for (int n = 0; n < 4; ++n)
#pragma unroll
      for (int r = 0; r < 4; ++r)
        ob[(size_t)(m * 16 + cr + r) * N_OUT + n * 16 + cc] = acc[m][n][r];
}

// ---------------- fallback (ws too small): fp32 reg-staging 128x128 ----------------
#define BM 128
#define BN 128
#define BK 64
#define MT (T_TOK / BM)
#define NTILE (N_OUT / BN)

__global__ void __launch_bounds__(256) gemm_fb(const float* __restrict__ af,
                                               const float* __restrict__ wf,
                                               const int* __restrict__ offs,
                                               float* __restrict__ out) {
  __shared__ __align__(16) ushort_t lsA[BM * BK];
  __shared__ __align__(16) ushort_t lsB[BN * BK];
  int bid = blockIdx.x;
  int wg = (bid & 7) * ((MT * NTILE) >> 3) + (bid >> 3);
  int tm = wg / NTILE, tn = wg - tm * NTILE;
  const int t = threadIdx.x, w = t >> 6, l = t & 63;
  const int row0 = tm * BM;
  int e = 0;
#pragma unroll
  for (int i = 1; i < NEXP; ++i) e += (row0 >= offs[i]) ? 1 : 0;
  const size_t wbase = (size_t)e * ((size_t)N_OUT * K_IN);
  f32x4 acc[4][4];
#pragma unroll
  for (int i = 0; i < 4; ++i)
#pragma unroll
    for (int j = 0; j < 4; ++j)
#pragma unroll
      for (int r = 0; r < 4; ++r) acc[i][j][r] = 0.f;
  const int wm = w >> 1, wn = w & 1;
  const int rA = wm * 64 + (l & 15), rB = wn * 64 + (l & 15);
  const int kgo = (l >> 4) * 8;
  for (int kt = 0; kt < K_IN / BK; ++kt) {
    const int k0 = kt * BK;
    if (kt) __syncthreads();
#pragma unroll
    for (int p = 0; p < 4; ++p) {
      const int ia = (p * 4 + w) * 64 + l;
      const float4* g = (const float4*)(af + (size_t)(row0 + (ia >> 3)) * K_IN +
                                        k0 + (ia & 7) * 8);
      float4 a = g[0], b = g[1];
      short8 v;
      v[0] = (short)f2bf(a.x); v[1] = (short)f2bf(a.y);
      v[2] = (short)f2bf(a.z); v[3] = (short)f2bf(a.w);
      v[4] = (short)f2bf(b.x); v[5] = (short)f2bf(b.y);
      v[6] = (short)f2bf(b.z); v[7] = (short)f2bf(b.w);
      *(short8*)&lsA[ia * 8] = v;
    }
#pragma unroll
    for (int p = 0; p < 4; ++p) {
      const int ib = (p * 4 + w) * 64 + l;
      const float4* g = (const float4*)(wf + wbase +
                                        (size_t)(tn * BN + (ib >> 3)) * K_IN +
                                        k0 + (ib & 7) * 8);
      float4 a = g[0], b = g[1];
      short8 v;
      v[0] = (short)f2bf(a.x); v[1] = (short)f2bf(a.y);
      v[2] = (short)f2bf(a.z); v[3] = (short)f2bf(a.w);
      v[4] = (short)f2bf(b.x); v[5] = (short)f2bf(b.y);
      v[6] = (short)f2bf(b.z); v[7] = (short)f2bf(b.w);
      *(short8*)&lsB[ib * 8] = v;
    }
    __syncthreads();
#pragma unroll
    for (int s = 0; s < 2; ++s) {
      const int ko = s * 32 + kgo;
      short8 aF[4], bFf[4];
#pragma unroll
      for (int i = 0; i < 4; ++i) aF[i] = *(const short8*)&lsA[(rA + i * 16) * BK + ko];
#pragma unroll
      for (int j = 0; j < 4; ++j) bFf[j] = *(const short8*)&lsB[(rB + j * 16) * BK + ko];
#pragma unroll
      for (int i = 0; i < 4; ++i)
#pragma unroll
        for (int j = 0; j < 4; ++j)
          acc[i][j] = __builtin_amdgcn_mfma_f32_16x16x32_bf16(aF[i], bFf[j],
                                                              acc[i][j], 0, 0, 0);
    }
  }
  const int cr = (l >> 4) * 4, cc = l & 15;
  float* ob = out + (size_t)(row0 + wm * 64) * N_OUT + tn * BN + wn * 64;
#pragma unroll
  for (int i = 0; i < 4; ++i)
#pragma unroll
    for (int j = 0; j < 4; ++j)
#pragma unroll
      for (int r = 0; r < 4; ++r)
        ob[(size_t)(i * 16 + cr + r) * N_OUT + j * 16 + cc] = acc[i][j][r];
}

extern "C" void kernel_launch(void* const* d_in, const int* in_sizes, int n_in,
                              void* d_out, int out_size, void* d_ws, size_t ws_size,
                              hipStream_t stream) {
  const float* x = (const float*)d_in[0];
  const float* wt = (const float*)d_in[1];
  const int* offs = (const int*)d_in[2];
  float* out = (float*)d_out;

  const size_t nA = (size_t)T_TOK * K_IN;
  const size_t nW = (size_t)NEXP * N_OUT * K_IN;
  const size_t need = (nA + nW) * sizeof(ushort_t);

  if (ws_size >= need) {
    ushort_t* abf = (ushort_t*)d_ws;
    ushort_t* wbf = abf + nA;
    cvt_kernel<<<2048, 256, 0, stream>>>(x, abf, (int)(nA / 8));
    cvt_kernel<<<2048, 256, 0, stream>>>(wt, wbf, (int)(nW / 8));
    gemm8<<<GRID2, 512, 0, stream>>>(abf, wbf, offs, out);
  } else {
    gemm_fb<<<MT * NTILE, 256, 0, stream>>>(x, wt, offs, out);
  }
}